// Round 7
// baseline (113.060 us; speedup 1.0000x reference)
//
#include <hip/hip_runtime.h>

#define NB 8
#define NN 1024
#define NH 32

// ---- warped-grid me(s,t) table ----
// u = s/(1+|s|/C) maps s in [-R,R] to u in [-U,U], U = C*R/(C+R).
#define FP 99              // grid points per axis; cells (FP-1)^2
#define CW 6.0f            // warp constant C
#define RW 7.5f            // range covered exactly
#define UW (CW * RW / (CW + RW))   // 10/3

__device__ __forceinline__ float leaky(float x) { return fmaxf(x, 0.01f * x); }

__device__ __forceinline__ float fast_tanh(float x) {
    float e = __builtin_amdgcn_exp2f(x * 2.88539008177792681f);
    return 1.0f - 2.0f * __builtin_amdgcn_rcpf(1.0f + e);
}

#define SWZ_ADD(v, imm) \
    v += __int_as_float(__builtin_amdgcn_ds_swizzle(__float_as_int(v), imm))

__device__ __forceinline__ unsigned bf16r(float f) {   // fp32 -> bf16 bits, RNE
    unsigned u = __float_as_uint(f);
    return (u + 0x7FFFu + ((u >> 16) & 1u)) >> 16;
}

// Edge-MLP scalar f(s,t); all weight reads wave-uniform (K$).
__device__ __forceinline__ float mlp_me(float s, float t,
    const float* __restrict__ Wm1, const float* __restrict__ bm1,
    const float* __restrict__ Wm2, const float* __restrict__ bm2,
    const float* __restrict__ Wm3, const float* __restrict__ bm3) {
    float h1[NH];
#pragma unroll
    for (int k = 0; k < NH; ++k)
        h1[k] = leaky(s * Wm1[k] + t * Wm1[32 + k] + bm1[k]);
    float acc[NH];
#pragma unroll
    for (int h = 0; h < NH; ++h) acc[h] = bm2[h];
#pragma unroll
    for (int k = 0; k < NH; ++k) {
#pragma unroll
        for (int h4 = 0; h4 < 8; ++h4) {
            const float4 wv = *(const float4*)(Wm2 + k * 32 + h4 * 4);
            acc[h4 * 4 + 0] = fmaf(h1[k], wv.x, acc[h4 * 4 + 0]);
            acc[h4 * 4 + 1] = fmaf(h1[k], wv.y, acc[h4 * 4 + 1]);
            acc[h4 * 4 + 2] = fmaf(h1[k], wv.z, acc[h4 * 4 + 2]);
            acc[h4 * 4 + 3] = fmaf(h1[k], wv.w, acc[h4 * 4 + 3]);
        }
    }
    float z = bm3[0];
#pragma unroll
    for (int h = 0; h < NH; ++h) z = fmaf(leaky(acc[h]), Wm3[h], z);
    return fast_tanh(z);
}

// ---------------- build warped-grid cells ----------------
// cell = { fp32 f00, bf16(f10-f00) | bf16(f01-f00)<<16 }
__global__ __launch_bounds__(256) void table_kernel(
    const float* __restrict__ Wm1, const float* __restrict__ bm1,
    const float* __restrict__ Wm2, const float* __restrict__ bm2,
    const float* __restrict__ Wm3, const float* __restrict__ bm3,
    uint2* __restrict__ tq) {
    const int gid = blockIdx.x * 256 + threadIdx.x;
    if (gid >= FP * FP) return;
    const int iy = gid / FP;
    const int ix = gid - iy * FP;
    if (ix >= FP - 1 || iy >= FP - 1) { tq[gid] = make_uint2(0u, 0u); return; }

    const float hu = 2.0f * UW / (float)(FP - 1);
    auto unwarp = [](float u) { return u / (1.0f - fabsf(u) / CW); };
    const float s0 = unwarp(fmaf((float)ix, hu, -UW));
    const float s1 = unwarp(fmaf((float)(ix + 1), hu, -UW));
    const float t0 = unwarp(fmaf((float)iy, hu, -UW));
    const float t1 = unwarp(fmaf((float)(iy + 1), hu, -UW));

    const float f00 = mlp_me(s0, t0, Wm1, bm1, Wm2, bm2, Wm3, bm3);
    const float f10 = mlp_me(s1, t0, Wm1, bm1, Wm2, bm2, Wm3, bm3);
    const float f01 = mlp_me(s0, t1, Wm1, bm1, Wm2, bm2, Wm3, bm3);

    uint2 cell;
    cell.x = __float_as_uint(f00);
    cell.y = bf16r(f10 - f00) | (bf16r(f01 - f00) << 16);
    tq[gid] = cell;
}

// ---------------- edge lookup + row sum + fused output MLP ----------------
// 1024 threads = 16 waves; wave owns one (b,i); LDS caps at 2 blocks/CU.
// Batch-8 three-phase inner loop, 4 accumulators; VGPR cap relaxed to let
// the compiler keep 16 vmem + 8 ds_read in flight per wave.
__global__ __launch_bounds__(1024, 5) void edge_out_kernel(
    const float* __restrict__ x, const float* __restrict__ A,
    const uint2* __restrict__ tq,
    const float* __restrict__ Wx1, const float* __restrict__ bx1,
    const float* __restrict__ Wx2, const float* __restrict__ bx2,
    const float* __restrict__ Wx3, const float* __restrict__ bx3,
    float* __restrict__ out) {
    __shared__ uint2 sfq[FP * FP];                     // 78,408 B

    const int tid = threadIdx.x;
    {
        const float4* __restrict__ src = (const float4*)tq;
        float4* dst = (float4*)sfq;
        for (int idx = tid; idx < (FP * FP) / 2; idx += 1024) dst[idx] = src[idx];
        if (tid == 0) sfq[FP * FP - 1] = tq[FP * FP - 1];
    }
    __syncthreads();

    const int wave = tid >> 6;
    const int lane = tid & 63;
    const int w    = blockIdx.x * 16 + wave;           // < 8192
    const int i    = w >> 3;
    const int b    = w & 7;
    const int node = b * NN + i;

    const float2 xi = ((const float2*)x)[node];        // wave-uniform
    const float2* __restrict__ xb = (const float2*)x + b * NN;
    const float* __restrict__ Arow = A + (size_t)i * NN;

    const float hu     = 2.0f * UW / (float)(FP - 1);
    const float inv_hu = 1.0f / hu;
    const float fhi    = (float)(FP - 1) - 0.001f;
    const float rcw    = 1.0f / CW;

    float ms0 = 0.0f, ms1 = 0.0f, ms2 = 0.0f, ms3 = 0.0f;
#pragma unroll
    for (int g = 0; g < 2; ++g) {
        // phase 1: batch global loads (16 independent vmem in flight)
        float2 xv[8]; float av[8];
#pragma unroll
        for (int q = 0; q < 8; ++q) {
            const int j = (g * 8 + q) * 64 + lane;
            xv[q] = xb[j];
            av[q] = Arow[j];
        }
        // phase 2: batch address math
        int   idxq[8];
        float asq[8], atq[8];
#pragma unroll
        for (int q = 0; q < 8; ++q) {
            const float s = xi.x + xv[q].x;
            const float t = xi.y + xv[q].y;
            const float us = s * __builtin_amdgcn_rcpf(fmaf(fabsf(s), rcw, 1.0f));
            const float ut = t * __builtin_amdgcn_rcpf(fmaf(fabsf(t), rcw, 1.0f));
            const float fs = fminf(fmaxf((us + UW) * inv_hu, 0.0f), fhi);
            const float ft = fminf(fmaxf((ut + UW) * inv_hu, 0.0f), fhi);
            const float fsf = floorf(fs), ftf = floorf(ft);
            asq[q] = fs - fsf;
            atq[q] = ft - ftf;
            idxq[q] = (int)ftf * FP + (int)fsf;
        }
        // phase 3: batch gathers (8 ds_read_b64 back-to-back)
        uint2 cqv[8];
#pragma unroll
        for (int q = 0; q < 8; ++q) cqv[q] = sfq[idxq[q]];
        // phase 4: interpolate + accumulate (4 independent chains)
#pragma unroll
        for (int q = 0; q < 8; ++q) {
            const float c00 = __uint_as_float(cqv[q].x);
            const float dcs = __uint_as_float(cqv[q].y << 16);
            const float dct = __uint_as_float(cqv[q].y & 0xFFFF0000u);
            const float me  = fmaf(atq[q], dct, fmaf(asq[q], dcs, c00));
            if      ((q & 3) == 0) ms0 = fmaf(me, av[q], ms0);
            else if ((q & 3) == 1) ms1 = fmaf(me, av[q], ms1);
            else if ((q & 3) == 2) ms2 = fmaf(me, av[q], ms2);
            else                   ms3 = fmaf(me, av[q], ms3);
        }
    }
    float msum = (ms0 + ms1) + (ms2 + ms3);

    // full-wave butterfly: every lane ends with the row sum
    SWZ_ADD(msum, 0x041F);
    SWZ_ADD(msum, 0x081F);
    SWZ_ADD(msum, 0x101F);
    SWZ_ADD(msum, 0x201F);
    SWZ_ADD(msum, 0x401F);
    msum += __shfl_xor(msum, 32, 64);

    // ---- fused output MLP (transient-k, no h1x array) ----
    const float rho = xi.x;
    const int h = lane & 31;
    float acc = bx2[h];
#pragma unroll
    for (int k = 0; k < NH; ++k) {
        const float h1k = leaky(fmaf(msum, Wx1[32 + k], fmaf(rho, Wx1[k], bx1[k])));
        acc = fmaf(h1k, Wx2[k * 32 + h], acc);
    }
    float sv = (lane < 32) ? leaky(acc) * Wx3[h] : 0.0f;
    SWZ_ADD(sv, 0x041F);
    SWZ_ADD(sv, 0x081F);
    SWZ_ADD(sv, 0x101F);
    SWZ_ADD(sv, 0x201F);
    SWZ_ADD(sv, 0x401F);
    sv += __shfl_xor(sv, 32, 64);
    if (lane == 0) out[node] = fast_tanh(sv + bx3[0]);
}

extern "C" void kernel_launch(void* const* d_in, const int* in_sizes, int n_in,
                              void* d_out, int out_size, void* d_ws, size_t ws_size,
                              hipStream_t stream) {
    const float* x   = (const float*)d_in[0];
    const float* A   = (const float*)d_in[1];
    const float* Wm1 = (const float*)d_in[2];
    const float* bm1 = (const float*)d_in[3];
    const float* Wm2 = (const float*)d_in[4];
    const float* bm2 = (const float*)d_in[5];
    const float* Wm3 = (const float*)d_in[6];
    const float* bm3 = (const float*)d_in[7];
    const float* Wx1 = (const float*)d_in[8];
    const float* bx1 = (const float*)d_in[9];
    const float* Wx2 = (const float*)d_in[10];
    const float* bx2 = (const float*)d_in[11];
    const float* Wx3 = (const float*)d_in[12];
    const float* bx3 = (const float*)d_in[13];

    uint2* tq  = (uint2*)d_ws;                         // FP*FP cells (78.4 KB)
    float* out = (float*)d_out;

    table_kernel<<<dim3((FP * FP + 255) / 256), dim3(256), 0, stream>>>(
        Wm1, bm1, Wm2, bm2, Wm3, bm3, tq);
    edge_out_kernel<<<dim3(NB * NN / 16), dim3(1024), 0, stream>>>(
        x, A, tq, Wx1, bx1, Wx2, bx2, Wx3, bx3, out);
}

// Round 8
// 110.993 us; speedup vs baseline: 1.0186x; 1.0186x over previous
//
#include <hip/hip_runtime.h>

#define NB 8
#define NN 1024
#define NH 32

// ---- warped-grid me(s,t) table ----
// u = s/(1+|s|/C) maps s in [-R,R] to u in [-U,U], U = C*R/(C+R).
#define FP 99              // grid points per axis; cells (FP-1)^2
#define CW 6.0f            // warp constant C
#define RW 7.5f            // range covered exactly
#define UW (CW * RW / (CW + RW))   // 10/3

__device__ __forceinline__ float leaky(float x) { return fmaxf(x, 0.01f * x); }

__device__ __forceinline__ float fast_tanh(float x) {
    float e = __builtin_amdgcn_exp2f(x * 2.88539008177792681f);
    return 1.0f - 2.0f * __builtin_amdgcn_rcpf(1.0f + e);
}

#define SWZ_ADD(v, imm) \
    v += __int_as_float(__builtin_amdgcn_ds_swizzle(__float_as_int(v), imm))

__device__ __forceinline__ unsigned bf16r(float f) {   // fp32 -> bf16 bits, RNE
    unsigned u = __float_as_uint(f);
    return (u + 0x7FFFu + ((u >> 16) & 1u)) >> 16;
}

// Edge-MLP scalar f(s,t); all weight reads wave-uniform (K$).
__device__ __forceinline__ float mlp_me(float s, float t,
    const float* __restrict__ Wm1, const float* __restrict__ bm1,
    const float* __restrict__ Wm2, const float* __restrict__ bm2,
    const float* __restrict__ Wm3, const float* __restrict__ bm3) {
    float h1[NH];
#pragma unroll
    for (int k = 0; k < NH; ++k)
        h1[k] = leaky(s * Wm1[k] + t * Wm1[32 + k] + bm1[k]);
    float acc[NH];
#pragma unroll
    for (int h = 0; h < NH; ++h) acc[h] = bm2[h];
#pragma unroll
    for (int k = 0; k < NH; ++k) {
#pragma unroll
        for (int h4 = 0; h4 < 8; ++h4) {
            const float4 wv = *(const float4*)(Wm2 + k * 32 + h4 * 4);
            acc[h4 * 4 + 0] = fmaf(h1[k], wv.x, acc[h4 * 4 + 0]);
            acc[h4 * 4 + 1] = fmaf(h1[k], wv.y, acc[h4 * 4 + 1]);
            acc[h4 * 4 + 2] = fmaf(h1[k], wv.z, acc[h4 * 4 + 2]);
            acc[h4 * 4 + 3] = fmaf(h1[k], wv.w, acc[h4 * 4 + 3]);
        }
    }
    float z = bm3[0];
#pragma unroll
    for (int h = 0; h < NH; ++h) z = fmaf(leaky(acc[h]), Wm3[h], z);
    return fast_tanh(z);
}

// ---------------- build warped-grid cells ----------------
// cell = { fp32 f00, bf16(f10-f00) | bf16(f01-f00)<<16 }
__global__ __launch_bounds__(256) void table_kernel(
    const float* __restrict__ Wm1, const float* __restrict__ bm1,
    const float* __restrict__ Wm2, const float* __restrict__ bm2,
    const float* __restrict__ Wm3, const float* __restrict__ bm3,
    uint2* __restrict__ tq) {
    const int gid = blockIdx.x * 256 + threadIdx.x;
    if (gid >= FP * FP) return;
    const int iy = gid / FP;
    const int ix = gid - iy * FP;
    if (ix >= FP - 1 || iy >= FP - 1) { tq[gid] = make_uint2(0u, 0u); return; }

    const float hu = 2.0f * UW / (float)(FP - 1);
    auto unwarp = [](float u) { return u / (1.0f - fabsf(u) / CW); };
    const float s0 = unwarp(fmaf((float)ix, hu, -UW));
    const float s1 = unwarp(fmaf((float)(ix + 1), hu, -UW));
    const float t0 = unwarp(fmaf((float)iy, hu, -UW));
    const float t1 = unwarp(fmaf((float)(iy + 1), hu, -UW));

    const float f00 = mlp_me(s0, t0, Wm1, bm1, Wm2, bm2, Wm3, bm3);
    const float f10 = mlp_me(s1, t0, Wm1, bm1, Wm2, bm2, Wm3, bm3);
    const float f01 = mlp_me(s0, t1, Wm1, bm1, Wm2, bm2, Wm3, bm3);

    uint2 cell;
    cell.x = __float_as_uint(f00);
    cell.y = bf16r(f10 - f00) | (bf16r(f01 - f00) << 16);
    tq[gid] = cell;
}

// ---------------- edge lookup + row sum + fused output MLP ----------------
// 1024 threads = 16 waves; wave owns one (b,i); 2 blocks/CU (78 KB LDS, 64 VGPR).
// j-paired inner loop: one float4 xb-load + one float2 A-load per TWO edges;
// 2 groups x 4 pair-iters so 8 vmem + 8 ds_read are in flight per group.
__global__ __launch_bounds__(1024, 8) void edge_out_kernel(
    const float* __restrict__ x, const float* __restrict__ A,
    const uint2* __restrict__ tq,
    const float* __restrict__ Wx1, const float* __restrict__ bx1,
    const float* __restrict__ Wx2, const float* __restrict__ bx2,
    const float* __restrict__ Wx3, const float* __restrict__ bx3,
    float* __restrict__ out) {
    __shared__ uint2 sfq[FP * FP];                     // 78,408 B

    const int tid = threadIdx.x;
    {
        const float4* __restrict__ src = (const float4*)tq;
        float4* dst = (float4*)sfq;
        for (int idx = tid; idx < (FP * FP) / 2; idx += 1024) dst[idx] = src[idx];
        if (tid == 0) sfq[FP * FP - 1] = tq[FP * FP - 1];
    }
    __syncthreads();

    const int wave = tid >> 6;
    const int lane = tid & 63;
    const int w    = blockIdx.x * 16 + wave;           // < 8192
    const int i    = w >> 3;
    const int b    = w & 7;
    const int node = b * NN + i;

    const float2 xi = ((const float2*)x)[node];        // wave-uniform
    const float4* __restrict__ xb4 = (const float4*)((const float2*)x + b * NN);
    const float2* __restrict__ Ar2 = (const float2*)(A + (size_t)i * NN);

    const float hu     = 2.0f * UW / (float)(FP - 1);
    const float inv_hu = 1.0f / hu;
    const float fhi    = (float)(FP - 1) - 0.001f;
    const float rcw    = 1.0f / CW;

    float ms0 = 0.0f, ms1 = 0.0f, ms2 = 0.0f, ms3 = 0.0f;
#pragma unroll
    for (int g = 0; g < 2; ++g) {
        // phase 1: batch loads — 4 float4 (xj pairs) + 4 float2 (A pairs)
        float4 xv[4]; float2 av[4];
#pragma unroll
        for (int q = 0; q < 4; ++q) {
            const int p = (g * 4 + q) * 64 + lane;     // pair index
            xv[q] = xb4[p];                            // nodes 2p, 2p+1
            av[q] = Ar2[p];
        }
        // phase 2: batch address math for 8 edges
        int   idxq[8];
        float asq[8], atq[8];
#pragma unroll
        for (int q = 0; q < 4; ++q) {
#pragma unroll
            for (int e = 0; e < 2; ++e) {
                const float s = xi.x + (e ? xv[q].z : xv[q].x);
                const float t = xi.y + (e ? xv[q].w : xv[q].y);
                const float us = s * __builtin_amdgcn_rcpf(fmaf(fabsf(s), rcw, 1.0f));
                const float ut = t * __builtin_amdgcn_rcpf(fmaf(fabsf(t), rcw, 1.0f));
                const float fs = fminf(fmaxf((us + UW) * inv_hu, 0.0f), fhi);
                const float ft = fminf(fmaxf((ut + UW) * inv_hu, 0.0f), fhi);
                const float fsf = floorf(fs), ftf = floorf(ft);
                asq[q * 2 + e] = fs - fsf;
                atq[q * 2 + e] = ft - ftf;
                idxq[q * 2 + e] = (int)ftf * FP + (int)fsf;
            }
        }
        // phase 3: batch gathers (8 ds_read_b64 back-to-back)
        uint2 cqv[8];
#pragma unroll
        for (int q = 0; q < 8; ++q) cqv[q] = sfq[idxq[q]];
        // phase 4: interpolate + accumulate (4 independent chains)
#pragma unroll
        for (int q = 0; q < 8; ++q) {
            const float c00 = __uint_as_float(cqv[q].x);
            const float dcs = __uint_as_float(cqv[q].y << 16);
            const float dct = __uint_as_float(cqv[q].y & 0xFFFF0000u);
            const float me  = fmaf(atq[q], dct, fmaf(asq[q], dcs, c00));
            const float aw  = (q & 1) ? av[q >> 1].y : av[q >> 1].x;
            if      ((q & 3) == 0) ms0 = fmaf(me, aw, ms0);
            else if ((q & 3) == 1) ms1 = fmaf(me, aw, ms1);
            else if ((q & 3) == 2) ms2 = fmaf(me, aw, ms2);
            else                   ms3 = fmaf(me, aw, ms3);
        }
    }
    float msum = (ms0 + ms1) + (ms2 + ms3);

    // full-wave butterfly: every lane ends with the row sum
    SWZ_ADD(msum, 0x041F);
    SWZ_ADD(msum, 0x081F);
    SWZ_ADD(msum, 0x101F);
    SWZ_ADD(msum, 0x201F);
    SWZ_ADD(msum, 0x401F);
    msum += __shfl_xor(msum, 32, 64);

    // ---- fused output MLP (transient-k, no h1x array) ----
    const float rho = xi.x;
    const int h = lane & 31;
    float acc = bx2[h];
#pragma unroll
    for (int k = 0; k < NH; ++k) {
        const float h1k = leaky(fmaf(msum, Wx1[32 + k], fmaf(rho, Wx1[k], bx1[k])));
        acc = fmaf(h1k, Wx2[k * 32 + h], acc);
    }
    float sv = (lane < 32) ? leaky(acc) * Wx3[h] : 0.0f;
    SWZ_ADD(sv, 0x041F);
    SWZ_ADD(sv, 0x081F);
    SWZ_ADD(sv, 0x101F);
    SWZ_ADD(sv, 0x201F);
    SWZ_ADD(sv, 0x401F);
    sv += __shfl_xor(sv, 32, 64);
    if (lane == 0) out[node] = fast_tanh(sv + bx3[0]);
}

extern "C" void kernel_launch(void* const* d_in, const int* in_sizes, int n_in,
                              void* d_out, int out_size, void* d_ws, size_t ws_size,
                              hipStream_t stream) {
    const float* x   = (const float*)d_in[0];
    const float* A   = (const float*)d_in[1];
    const float* Wm1 = (const float*)d_in[2];
    const float* bm1 = (const float*)d_in[3];
    const float* Wm2 = (const float*)d_in[4];
    const float* bm2 = (const float*)d_in[5];
    const float* Wm3 = (const float*)d_in[6];
    const float* bm3 = (const float*)d_in[7];
    const float* Wx1 = (const float*)d_in[8];
    const float* bx1 = (const float*)d_in[9];
    const float* Wx2 = (const float*)d_in[10];
    const float* bx2 = (const float*)d_in[11];
    const float* Wx3 = (const float*)d_in[12];
    const float* bx3 = (const float*)d_in[13];

    uint2* tq  = (uint2*)d_ws;                         // FP*FP cells (78.4 KB)
    float* out = (float*)d_out;

    table_kernel<<<dim3((FP * FP + 255) / 256), dim3(256), 0, stream>>>(
        Wm1, bm1, Wm2, bm2, Wm3, bm3, tq);
    edge_out_kernel<<<dim3(NB * NN / 16), dim3(1024), 0, stream>>>(
        x, A, tq, Wx1, bx1, Wx2, bx2, Wx3, bx3, out);
}

// Round 9
// 103.579 us; speedup vs baseline: 1.0915x; 1.0716x over previous
//
#include <hip/hip_runtime.h>

#define NB 8
#define NN 1024
#define NH 32

// ---- warped-grid me(s,t) table ----
// u = s/(1+|s|/C) maps s in [-R,R] to u in [-U,U], U = C*R/(C+R).
#define FP 99              // grid points per axis; cells (FP-1)^2
#define CW 6.0f            // warp constant C
#define RW 7.5f            // range covered exactly
#define UW (CW * RW / (CW + RW))   // 10/3

__device__ __forceinline__ float leaky(float x) { return fmaxf(x, 0.01f * x); }

__device__ __forceinline__ float fast_tanh(float x) {
    float e = __builtin_amdgcn_exp2f(x * 2.88539008177792681f);
    return 1.0f - 2.0f * __builtin_amdgcn_rcpf(1.0f + e);
}

#define SWZ_ADD(v, imm) \
    v += __int_as_float(__builtin_amdgcn_ds_swizzle(__float_as_int(v), imm))

__device__ __forceinline__ unsigned bf16r(float f) {   // fp32 -> bf16 bits, RNE
    unsigned u = __float_as_uint(f);
    return (u + 0x7FFFu + ((u >> 16) & 1u)) >> 16;
}

// ---------------- eval: f(s,t) at every grid point, one point per thread ----
// Weights staged in LDS once per block; k-loop weight reads are wave-uniform
// ds_read_b128 broadcasts that pipeline under the FMA stream.
__global__ __launch_bounds__(256) void eval_kernel(
    const float* __restrict__ Wm1, const float* __restrict__ bm1,
    const float* __restrict__ Wm2, const float* __restrict__ bm2,
    const float* __restrict__ Wm3, const float* __restrict__ bm3,
    float* __restrict__ tabf) {
    __shared__ __align__(16) float sW2[1024];
    __shared__ float sW1[64], sb1[32], sb2[32], sW3[32];
    __shared__ float sb3;
    const int tid = threadIdx.x;
#pragma unroll
    for (int q = 0; q < 4; ++q) sW2[tid + 256 * q] = Wm2[tid + 256 * q];
    if (tid < 64) sW1[tid] = Wm1[tid];
    if (tid < 32) { sb1[tid] = bm1[tid]; sb2[tid] = bm2[tid]; sW3[tid] = Wm3[tid]; }
    if (tid == 0) sb3 = bm3[0];
    __syncthreads();

    const int gid = blockIdx.x * 256 + tid;
    if (gid >= FP * FP) return;
    const int iy = gid / FP;
    const int ix = gid - iy * FP;

    const float hu = 2.0f * UW / (float)(FP - 1);
    const float us = fmaf((float)ix, hu, -UW);
    const float ut = fmaf((float)iy, hu, -UW);
    const float s = us / (1.0f - fabsf(us) / CW);      // unwarp (exact div)
    const float t = ut / (1.0f - fabsf(ut) / CW);

    float h1[NH];
#pragma unroll
    for (int k = 0; k < NH; ++k)
        h1[k] = leaky(s * sW1[k] + t * sW1[32 + k] + sb1[k]);

    float acc[NH];
#pragma unroll
    for (int h = 0; h < NH; ++h) acc[h] = sb2[h];
#pragma unroll
    for (int k = 0; k < NH; ++k) {
#pragma unroll
        for (int h4 = 0; h4 < 8; ++h4) {
            const float4 wv = *(const float4*)(sW2 + k * 32 + h4 * 4);
            acc[h4 * 4 + 0] = fmaf(h1[k], wv.x, acc[h4 * 4 + 0]);
            acc[h4 * 4 + 1] = fmaf(h1[k], wv.y, acc[h4 * 4 + 1]);
            acc[h4 * 4 + 2] = fmaf(h1[k], wv.z, acc[h4 * 4 + 2]);
            acc[h4 * 4 + 3] = fmaf(h1[k], wv.w, acc[h4 * 4 + 3]);
        }
    }
    float z = sb3;
#pragma unroll
    for (int h = 0; h < NH; ++h) z = fmaf(leaky(acc[h]), sW3[h], z);
    tabf[gid] = fast_tanh(z);
}

// ---------------- assemble packed cells from point values ----------------
// cell = { fp32 f00, bf16(f10-f00) | bf16(f01-f00)<<16 }
__global__ __launch_bounds__(256) void assemble_kernel(
    const float* __restrict__ tabf, uint2* __restrict__ tq) {
    const int gid = blockIdx.x * 256 + threadIdx.x;
    if (gid >= FP * FP) return;
    const int iy = gid / FP;
    const int ix = gid - iy * FP;
    if (ix >= FP - 1 || iy >= FP - 1) { tq[gid] = make_uint2(0u, 0u); return; }
    const float f00 = tabf[gid];
    const float f10 = tabf[gid + 1];
    const float f01 = tabf[gid + FP];
    uint2 cell;
    cell.x = __float_as_uint(f00);
    cell.y = bf16r(f10 - f00) | (bf16r(f01 - f00) << 16);
    tq[gid] = cell;
}

// ---------------- edge lookup + row sum + fused output MLP ----------------
// 1024 threads = 16 waves; wave owns one (b,i); 2 blocks/CU (78 KB LDS, 64 VGPR).
// j-paired inner loop: one float4 xb-load + one float2 A-load per TWO edges.
__global__ __launch_bounds__(1024, 8) void edge_out_kernel(
    const float* __restrict__ x, const float* __restrict__ A,
    const uint2* __restrict__ tq,
    const float* __restrict__ Wx1, const float* __restrict__ bx1,
    const float* __restrict__ Wx2, const float* __restrict__ bx2,
    const float* __restrict__ Wx3, const float* __restrict__ bx3,
    float* __restrict__ out) {
    __shared__ uint2 sfq[FP * FP];                     // 78,408 B

    const int tid = threadIdx.x;
    {
        const float4* __restrict__ src = (const float4*)tq;
        float4* dst = (float4*)sfq;
        for (int idx = tid; idx < (FP * FP) / 2; idx += 1024) dst[idx] = src[idx];
        if (tid == 0) sfq[FP * FP - 1] = tq[FP * FP - 1];
    }
    __syncthreads();

    const int wave = tid >> 6;
    const int lane = tid & 63;
    const int w    = blockIdx.x * 16 + wave;           // < 8192
    const int i    = w >> 3;
    const int b    = w & 7;
    const int node = b * NN + i;

    const float2 xi = ((const float2*)x)[node];        // wave-uniform
    const float4* __restrict__ xb4 = (const float4*)((const float2*)x + b * NN);
    const float2* __restrict__ Ar2 = (const float2*)(A + (size_t)i * NN);

    const float hu     = 2.0f * UW / (float)(FP - 1);
    const float inv_hu = 1.0f / hu;
    const float fhi    = (float)(FP - 1) - 0.001f;
    const float rcw    = 1.0f / CW;

    float ms0 = 0.0f, ms1 = 0.0f, ms2 = 0.0f, ms3 = 0.0f;
#pragma unroll
    for (int g = 0; g < 2; ++g) {
        float4 xv[4]; float2 av[4];
#pragma unroll
        for (int q = 0; q < 4; ++q) {
            const int p = (g * 4 + q) * 64 + lane;     // pair index
            xv[q] = xb4[p];                            // nodes 2p, 2p+1
            av[q] = Ar2[p];
        }
        int   idxq[8];
        float asq[8], atq[8];
#pragma unroll
        for (int q = 0; q < 4; ++q) {
#pragma unroll
            for (int e = 0; e < 2; ++e) {
                const float s = xi.x + (e ? xv[q].z : xv[q].x);
                const float t = xi.y + (e ? xv[q].w : xv[q].y);
                const float us = s * __builtin_amdgcn_rcpf(fmaf(fabsf(s), rcw, 1.0f));
                const float ut = t * __builtin_amdgcn_rcpf(fmaf(fabsf(t), rcw, 1.0f));
                const float fs = fminf(fmaxf((us + UW) * inv_hu, 0.0f), fhi);
                const float ft = fminf(fmaxf((ut + UW) * inv_hu, 0.0f), fhi);
                const float fsf = floorf(fs), ftf = floorf(ft);
                asq[q * 2 + e] = fs - fsf;
                atq[q * 2 + e] = ft - ftf;
                idxq[q * 2 + e] = (int)ftf * FP + (int)fsf;
            }
        }
        uint2 cqv[8];
#pragma unroll
        for (int q = 0; q < 8; ++q) cqv[q] = sfq[idxq[q]];
#pragma unroll
        for (int q = 0; q < 8; ++q) {
            const float c00 = __uint_as_float(cqv[q].x);
            const float dcs = __uint_as_float(cqv[q].y << 16);
            const float dct = __uint_as_float(cqv[q].y & 0xFFFF0000u);
            const float me  = fmaf(atq[q], dct, fmaf(asq[q], dcs, c00));
            const float aw  = (q & 1) ? av[q >> 1].y : av[q >> 1].x;
            if      ((q & 3) == 0) ms0 = fmaf(me, aw, ms0);
            else if ((q & 3) == 1) ms1 = fmaf(me, aw, ms1);
            else if ((q & 3) == 2) ms2 = fmaf(me, aw, ms2);
            else                   ms3 = fmaf(me, aw, ms3);
        }
    }
    float msum = (ms0 + ms1) + (ms2 + ms3);

    // full-wave butterfly: every lane ends with the row sum
    SWZ_ADD(msum, 0x041F);
    SWZ_ADD(msum, 0x081F);
    SWZ_ADD(msum, 0x101F);
    SWZ_ADD(msum, 0x201F);
    SWZ_ADD(msum, 0x401F);
    msum += __shfl_xor(msum, 32, 64);

    // ---- fused output MLP (transient-k, no h1x array) ----
    const float rho = xi.x;
    const int h = lane & 31;
    float acc = bx2[h];
#pragma unroll
    for (int k = 0; k < NH; ++k) {
        const float h1k = leaky(fmaf(msum, Wx1[32 + k], fmaf(rho, Wx1[k], bx1[k])));
        acc = fmaf(h1k, Wx2[k * 32 + h], acc);
    }
    float sv = (lane < 32) ? leaky(acc) * Wx3[h] : 0.0f;
    SWZ_ADD(sv, 0x041F);
    SWZ_ADD(sv, 0x081F);
    SWZ_ADD(sv, 0x101F);
    SWZ_ADD(sv, 0x201F);
    SWZ_ADD(sv, 0x401F);
    sv += __shfl_xor(sv, 32, 64);
    if (lane == 0) out[node] = fast_tanh(sv + bx3[0]);
}

extern "C" void kernel_launch(void* const* d_in, const int* in_sizes, int n_in,
                              void* d_out, int out_size, void* d_ws, size_t ws_size,
                              hipStream_t stream) {
    const float* x   = (const float*)d_in[0];
    const float* A   = (const float*)d_in[1];
    const float* Wm1 = (const float*)d_in[2];
    const float* bm1 = (const float*)d_in[3];
    const float* Wm2 = (const float*)d_in[4];
    const float* bm2 = (const float*)d_in[5];
    const float* Wm3 = (const float*)d_in[6];
    const float* bm3 = (const float*)d_in[7];
    const float* Wx1 = (const float*)d_in[8];
    const float* bx1 = (const float*)d_in[9];
    const float* Wx2 = (const float*)d_in[10];
    const float* bx2 = (const float*)d_in[11];
    const float* Wx3 = (const float*)d_in[12];
    const float* bx3 = (const float*)d_in[13];

    uint2* tq   = (uint2*)d_ws;                        // FP*FP cells (78.4 KB)
    float* tabf = (float*)(tq + FP * FP);              // FP*FP point values
    float* out  = (float*)d_out;

    const int nblk = (FP * FP + 255) / 256;
    eval_kernel<<<dim3(nblk), dim3(256), 0, stream>>>(
        Wm1, bm1, Wm2, bm2, Wm3, bm3, tabf);
    assemble_kernel<<<dim3(nblk), dim3(256), 0, stream>>>(tabf, tq);
    edge_out_kernel<<<dim3(NB * NN / 16), dim3(1024), 0, stream>>>(
        x, A, tq, Wx1, bx1, Wx2, bx2, Wx3, bx3, out);
}

// Round 10
// 95.158 us; speedup vs baseline: 1.1881x; 1.0885x over previous
//
#include <hip/hip_runtime.h>

#define NB 8
#define NN 1024
#define NH 32

// ---- warped-grid me(s,t) table ----
// u = s/(1+|s|/C) maps s in [-R,R] to u in [-U,U], U = C*R/(C+R).
#define FP 99              // grid points per axis; cells (FP-1)^2
#define CW 6.0f            // warp constant C
#define RW 7.5f            // range covered exactly
#define UW (CW * RW / (CW + RW))   // 10/3

__device__ __forceinline__ float leaky(float x) { return fmaxf(x, 0.01f * x); }

__device__ __forceinline__ float fast_tanh(float x) {
    float e = __builtin_amdgcn_exp2f(x * 2.88539008177792681f);
    return 1.0f - 2.0f * __builtin_amdgcn_rcpf(1.0f + e);
}

#define SWZ_ADD(v, imm) \
    v += __int_as_float(__builtin_amdgcn_ds_swizzle(__float_as_int(v), imm))

__device__ __forceinline__ unsigned bf16r(float f) {   // fp32 -> bf16 bits, RNE
    unsigned u = __float_as_uint(f);
    return (u + 0x7FFFu + ((u >> 16) & 1u)) >> 16;
}

// ---------------- eval: transposed — lane&31 = hidden channel h ----------------
// One wave evaluates TWO grid points (lane>>5 = which). Per k: h1k computed
// per-lane from wave-uniform Wm1/bm1 (K$ scalar loads); Wm2[k*32+h] is one
// coalesced 128B vector load (L1-hot). Butterfly-reduce over the 32-lane half.
__global__ __launch_bounds__(256) void eval_kernel(
    const float* __restrict__ Wm1, const float* __restrict__ bm1,
    const float* __restrict__ Wm2, const float* __restrict__ bm2,
    const float* __restrict__ Wm3, const float* __restrict__ bm3,
    float* __restrict__ tabf) {
    const int tid  = threadIdx.x;
    const int wav  = blockIdx.x * 4 + (tid >> 6);
    const int lane = tid & 63;
    const int half = lane >> 5;
    const int h    = lane & 31;
    const int p    = wav * 2 + half;               // grid-point id
    const bool valid = p < FP * FP;
    const int pp = valid ? p : 0;
    const int iy = pp / FP;
    const int ix = pp - iy * FP;

    const float hu = 2.0f * UW / (float)(FP - 1);
    const float us = fmaf((float)ix, hu, -UW);
    const float ut = fmaf((float)iy, hu, -UW);
    const float s = us / (1.0f - fabsf(us) / CW);  // unwarp (exact div)
    const float t = ut / (1.0f - fabsf(ut) / CW);

    float acc = bm2[h];
#pragma unroll
    for (int k = 0; k < NH; ++k) {
        const float h1k = leaky(s * Wm1[k] + t * Wm1[32 + k] + bm1[k]);
        acc = fmaf(h1k, Wm2[k * 32 + h], acc);
    }
    float v = leaky(acc) * Wm3[h];
    SWZ_ADD(v, 0x041F);   // xor 1   (ds_swizzle works within 32-lane groups)
    SWZ_ADD(v, 0x081F);   // xor 2
    SWZ_ADD(v, 0x101F);   // xor 4
    SWZ_ADD(v, 0x201F);   // xor 8
    SWZ_ADD(v, 0x401F);   // xor 16
    if (valid && h == 0) tabf[p] = fast_tanh(v + bm3[0]);
}

// ---------------- edge lookup + row sum + fused output MLP ----------------
// 1024 threads = 16 waves; wave owns one (b,i); 2 blocks/CU (78 KB LDS, 64 VGPR).
// Staging builds packed cells inline from tabf (L2-hot coalesced reads):
//   cell = { fp32 f00, bf16(f10-f00) | bf16(f01-f00)<<16 }
__global__ __launch_bounds__(1024, 8) void edge_out_kernel(
    const float* __restrict__ x, const float* __restrict__ A,
    const float* __restrict__ tabf,
    const float* __restrict__ Wx1, const float* __restrict__ bx1,
    const float* __restrict__ Wx2, const float* __restrict__ bx2,
    const float* __restrict__ Wx3, const float* __restrict__ bx3,
    float* __restrict__ out) {
    __shared__ uint2 sfq[FP * FP];                     // 78,408 B

    const int tid = threadIdx.x;
    for (int gid = tid; gid < FP * FP; gid += 1024) {
        const int giy = gid / FP;
        const int gix = gid - giy * FP;
        const float f00 = tabf[gid];
        const float f10 = tabf[(gix < FP - 1) ? gid + 1 : gid];
        const float f01 = tabf[(giy < FP - 1) ? gid + FP : gid];
        uint2 cell;
        cell.x = __float_as_uint(f00);
        cell.y = bf16r(f10 - f00) | (bf16r(f01 - f00) << 16);
        sfq[gid] = cell;                               // border cells unused
    }
    __syncthreads();

    const int wave = tid >> 6;
    const int lane = tid & 63;
    const int w    = blockIdx.x * 16 + wave;           // < 8192
    const int i    = w >> 3;
    const int b    = w & 7;
    const int node = b * NN + i;

    const float2 xi = ((const float2*)x)[node];        // wave-uniform
    const float4* __restrict__ xb4 = (const float4*)((const float2*)x + b * NN);
    const float2* __restrict__ Ar2 = (const float2*)(A + (size_t)i * NN);

    const float hu     = 2.0f * UW / (float)(FP - 1);
    const float inv_hu = 1.0f / hu;
    const float fhi    = (float)(FP - 1) - 0.001f;
    const float rcw    = 1.0f / CW;

    float ms0 = 0.0f, ms1 = 0.0f, ms2 = 0.0f, ms3 = 0.0f;
#pragma unroll
    for (int g = 0; g < 2; ++g) {
        float4 xv[4]; float2 av[4];
#pragma unroll
        for (int q = 0; q < 4; ++q) {
            const int p = (g * 4 + q) * 64 + lane;     // pair index
            xv[q] = xb4[p];                            // nodes 2p, 2p+1
            av[q] = Ar2[p];
        }
        int   idxq[8];
        float asq[8], atq[8];
#pragma unroll
        for (int q = 0; q < 4; ++q) {
#pragma unroll
            for (int e = 0; e < 2; ++e) {
                const float s = xi.x + (e ? xv[q].z : xv[q].x);
                const float t = xi.y + (e ? xv[q].w : xv[q].y);
                const float us = s * __builtin_amdgcn_rcpf(fmaf(fabsf(s), rcw, 1.0f));
                const float ut = t * __builtin_amdgcn_rcpf(fmaf(fabsf(t), rcw, 1.0f));
                const float fs = fminf(fmaxf((us + UW) * inv_hu, 0.0f), fhi);
                const float ft = fminf(fmaxf((ut + UW) * inv_hu, 0.0f), fhi);
                const float fsf = floorf(fs), ftf = floorf(ft);
                asq[q * 2 + e] = fs - fsf;
                atq[q * 2 + e] = ft - ftf;
                idxq[q * 2 + e] = (int)ftf * FP + (int)fsf;
            }
        }
        uint2 cqv[8];
#pragma unroll
        for (int q = 0; q < 8; ++q) cqv[q] = sfq[idxq[q]];
#pragma unroll
        for (int q = 0; q < 8; ++q) {
            const float c00 = __uint_as_float(cqv[q].x);
            const float dcs = __uint_as_float(cqv[q].y << 16);
            const float dct = __uint_as_float(cqv[q].y & 0xFFFF0000u);
            const float me  = fmaf(atq[q], dct, fmaf(asq[q], dcs, c00));
            const float aw  = (q & 1) ? av[q >> 1].y : av[q >> 1].x;
            if      ((q & 3) == 0) ms0 = fmaf(me, aw, ms0);
            else if ((q & 3) == 1) ms1 = fmaf(me, aw, ms1);
            else if ((q & 3) == 2) ms2 = fmaf(me, aw, ms2);
            else                   ms3 = fmaf(me, aw, ms3);
        }
    }
    float msum = (ms0 + ms1) + (ms2 + ms3);

    // full-wave butterfly: every lane ends with the row sum
    SWZ_ADD(msum, 0x041F);
    SWZ_ADD(msum, 0x081F);
    SWZ_ADD(msum, 0x101F);
    SWZ_ADD(msum, 0x201F);
    SWZ_ADD(msum, 0x401F);
    msum += __shfl_xor(msum, 32, 64);

    // ---- fused output MLP (transient-k, no h1x array) ----
    const float rho = xi.x;
    const int h = lane & 31;
    float acc = bx2[h];
#pragma unroll
    for (int k = 0; k < NH; ++k) {
        const float h1k = leaky(fmaf(msum, Wx1[32 + k], fmaf(rho, Wx1[k], bx1[k])));
        acc = fmaf(h1k, Wx2[k * 32 + h], acc);
    }
    float sv = (lane < 32) ? leaky(acc) * Wx3[h] : 0.0f;
    SWZ_ADD(sv, 0x041F);
    SWZ_ADD(sv, 0x081F);
    SWZ_ADD(sv, 0x101F);
    SWZ_ADD(sv, 0x201F);
    SWZ_ADD(sv, 0x401F);
    sv += __shfl_xor(sv, 32, 64);
    if (lane == 0) out[node] = fast_tanh(sv + bx3[0]);
}

extern "C" void kernel_launch(void* const* d_in, const int* in_sizes, int n_in,
                              void* d_out, int out_size, void* d_ws, size_t ws_size,
                              hipStream_t stream) {
    const float* x   = (const float*)d_in[0];
    const float* A   = (const float*)d_in[1];
    const float* Wm1 = (const float*)d_in[2];
    const float* bm1 = (const float*)d_in[3];
    const float* Wm2 = (const float*)d_in[4];
    const float* bm2 = (const float*)d_in[5];
    const float* Wm3 = (const float*)d_in[6];
    const float* bm3 = (const float*)d_in[7];
    const float* Wx1 = (const float*)d_in[8];
    const float* bx1 = (const float*)d_in[9];
    const float* Wx2 = (const float*)d_in[10];
    const float* bx2 = (const float*)d_in[11];
    const float* Wx3 = (const float*)d_in[12];
    const float* bx3 = (const float*)d_in[13];

    float* tabf = (float*)d_ws;                        // FP*FP point values (39 KB)
    float* out  = (float*)d_out;

    const int npairs = (FP * FP + 1) / 2;              // waves needed
    const int nblk   = (npairs + 3) / 4;               // 4 waves per block
    eval_kernel<<<dim3(nblk), dim3(256), 0, stream>>>(
        Wm1, bm1, Wm2, bm2, Wm3, bm3, tabf);
    edge_out_kernel<<<dim3(NB * NN / 16), dim3(1024), 0, stream>>>(
        x, A, tabf, Wx1, bx1, Wx2, bx2, Wx3, bx3, out);
}